// Round 5
// baseline (292.898 us; speedup 1.0000x reference)
//
#include <hip/hip_runtime.h>
#include <stdint.h>

typedef unsigned short u16;
typedef unsigned int   u32;
typedef __bf16 bf16x8 __attribute__((ext_vector_type(8)));
typedef float  f32x4  __attribute__((ext_vector_type(4)));
typedef u32    u32x4  __attribute__((ext_vector_type(4)));

#define L_IN 784
#define KPAD 832
#define NSTEP 25          // 25 x 32 = 800 >= 784 (B zero-padded to 832)

__device__ __forceinline__ u32 f2bf(float f){
    u32 u = __float_as_uint(f);
    return (u + 0x7fffu + ((u >> 16) & 1u)) >> 16;   // RNE truncate to bf16
}
__device__ __forceinline__ float bf2f(u32 s){ return __uint_as_float(s << 16); }

// ---------------------------------------------------------------------------
// K0: W0 [784][128] f32 -> Wt [13][128][64] bf16 (kt-major, col, k-in-tile).
// Zero-pad k >= 784. One-time tiny kernel.
// ---------------------------------------------------------------------------
__global__ void prep_w0(const float* __restrict__ W0, u16* __restrict__ Wt){
    int idx = blockIdx.x * 256 + threadIdx.x;        // 13*8192 = 106496 total
    if (idx >= KPAD * 128) return;
    int kin = idx & 63, col = (idx >> 6) & 127, kt = idx >> 13;
    int k = kt * 64 + kin;
    float v = (k < L_IN) ? W0[k * 128 + col] : 0.f;
    Wt[idx] = (u16)f2bf(v);
}

// ---------------------------------------------------------------------------
// K1: x = relu(h @ W0 + b0). Wave-independent streaming GEMM:
//  - one wave owns 16 rows, sweeps K in 25 steps of 32; NO barriers, NO LDS.
//  - per step: 8 B loads (L1/L2-resident Wt) issued FIRST, then 2-load A
//    prefetch for the NEXT step (younger in the vmcnt FIFO -> the wait for B
//    before MFMA leaves the A prefetch in flight), sched_barrier(0), 8 MFMA.
//  - latency hidden by wave count (TLP), not per-wave ILP: ~16-20 independent
//    waves/CU each keep >=1KB in flight.
// ---------------------------------------------------------------------------
__global__ __launch_bounds__(256)
void fc_gemm(const float* __restrict__ hG, const u16* __restrict__ Wt,
             const float* __restrict__ b0, u16* __restrict__ xbf, int N){
    const int lane = threadIdx.x & 63;
    const int wv   = threadIdx.x >> 6;
    const int lr   = lane & 15;          // A-row / B-col within 16
    const int lk   = lane >> 4;          // k-chunk slot 0..3 (8 elems)
    const long mt  = (long)blockIdx.x * 4 + wv;      // wave tile id
    if (mt * 16 >= (long)N) return;

    long row = mt * 16 + lr;
    if (row >= (long)N) row = N - 1;     // clamp; store is guarded
    const float* rowp = hG + row * L_IN;

    f32x4 acc[8];
    #pragma unroll
    for (int nt = 0; nt < 8; ++nt) acc[nt] = (f32x4)0.f;

    f32x4 a0A, a1A, a0B, a1B;            // A double-buffer (static names)

    auto issueA = [&](int step, f32x4& a0, f32x4& a1){
        int k0 = step * 32 + lk * 8;
        int off = (k0 <= L_IN - 8) ? k0 : 0;   // clamp: garbage * B-pad(0) = 0
        a0 = *(const f32x4*)(rowp + off);
        a1 = *(const f32x4*)(rowp + off + 4);
    };
    auto compute = [&](int step, const f32x4& a0, const f32x4& a1, int nextStep,
                       f32x4& na0, f32x4& na1){
        // B loads first (oldest), A prefetch second (youngest): the wait for
        // B before MFMA is vmcnt(2), keeping next A in flight.
        const u16* wp = Wt + (step >> 1) * 8192 + (step & 1) * 32 + lk * 8 + lr * 64;
        bf16x8 bfr[8];
        #pragma unroll
        for (int nt = 0; nt < 8; ++nt)
            bfr[nt] = *(const bf16x8*)(wp + nt * 1024);
        if (nextStep < NSTEP) issueA(nextStep, na0, na1);
        __builtin_amdgcn_sched_barrier(0);
        bf16x8 af;
        #pragma unroll
        for (int j = 0; j < 4; ++j){
            af[j]     = (__bf16)a0[j];
            af[4 + j] = (__bf16)a1[j];
        }
        #pragma unroll
        for (int nt = 0; nt < 8; ++nt)
            acc[nt] = __builtin_amdgcn_mfma_f32_16x16x32_bf16(af, bfr[nt], acc[nt], 0, 0, 0);
    };

    issueA(0, a0A, a1A);
    #pragma unroll 1
    for (int s2 = 0; s2 < (NSTEP - 1) / 2; ++s2){        // 12 double-steps
        compute(2 * s2,     a0A, a1A, 2 * s2 + 1, a0B, a1B);
        compute(2 * s2 + 1, a0B, a1B, 2 * s2 + 2, a0A, a1A);
    }
    compute(NSTEP - 1, a0A, a1A, NSTEP, a0B, a1B);       // step 24

    // ---- epilogue: + bias, relu, store bf16 ----
    #pragma unroll
    for (int nt = 0; nt < 8; ++nt){
        int col = nt * 16 + lr;
        float bias = b0[col];
        long row0 = mt * 16 + lk * 4;
        #pragma unroll
        for (int r = 0; r < 4; ++r){
            long rr = row0 + r;
            if (rr < (long)N){
                float v = acc[nt][r] + bias;
                v = v > 0.f ? v : 0.f;
                xbf[(size_t)rr * 128 + col] = (u16)f2bf(v);
            }
        }
    }
}

// ---------------------------------------------------------------------------
// K2: gated attention logits + exp + block pooling partials.
// ---------------------------------------------------------------------------
__global__ __launch_bounds__(256, 2)
void attn_pool(const u16* __restrict__ xbf,
               const float* __restrict__ Wa, const float* __restrict__ ba,
               const float* __restrict__ Wb, const float* __restrict__ bb,
               const float* __restrict__ Wc, const float* __restrict__ bc,
               float* __restrict__ partials, float* __restrict__ psum, int N){
    __shared__ __align__(16) float Wa_s[4096], Wb_s[4096];
    __shared__ float ba_s[64], bb_s[64], Wc_s[64], bc_s[2];
    __shared__ float eA[128][2];

    const int t  = threadIdx.x;
    const int gb = blockIdx.x;

    for (int i = t; i < 4096; i += 256){ Wa_s[i] = Wa[i]; Wb_s[i] = Wb[i]; }
    if (t < 64){ ba_s[t] = ba[t]; bb_s[t] = bb[t]; Wc_s[t] = Wc[t]; }
    if (t < 2)  bc_s[t] = bc[t];
    __syncthreads();

    // ---- phase 1: attention logit per (instance, head) ----
    {
        const int inst = t & 127, hh = t >> 7;
        const long gi = (long)gb * 128 + inst;
        float aa[32], ag[32];
        #pragma unroll
        for (int d = 0; d < 32; ++d){ aa[d] = ba_s[hh*32+d]; ag[d] = bb_s[hh*32+d]; }
        const float* wa = &Wa_s[hh * 2048];
        const float* wb = &Wb_s[hh * 2048];
        const u16*   xp = xbf + gi * 128 + hh * 64;
        for (int c = 0; c < 8; ++c){
            u32x4 xc = *(const u32x4*)(xp + c * 8);
            #pragma unroll
            for (int s8 = 0; s8 < 8; ++s8){
                u32 uw = xc[s8 >> 1];
                float xv = bf2f((s8 & 1) ? (uw >> 16) : (uw & 0xffffu));
                const int s = c * 8 + s8;
                #pragma unroll
                for (int q = 0; q < 8; ++q){
                    f32x4 w4 = *(const f32x4*)(wa + s * 32 + q * 4);
                    f32x4 v4 = *(const f32x4*)(wb + s * 32 + q * 4);
                    aa[q*4+0] += xv * w4[0]; aa[q*4+1] += xv * w4[1];
                    aa[q*4+2] += xv * w4[2]; aa[q*4+3] += xv * w4[3];
                    ag[q*4+0] += xv * v4[0]; ag[q*4+1] += xv * v4[1];
                    ag[q*4+2] += xv * v4[2]; ag[q*4+3] += xv * v4[3];
                }
            }
        }
        float A = bc_s[hh];
        #pragma unroll
        for (int d = 0; d < 32; ++d){
            float av = tanhf(aa[d]);
            float gv = 1.f / (1.f + expf(-ag[d]));
            A += av * gv * Wc_s[hh*32+d];
        }
        // exp without max-subtraction: |A| <= sum|Wc|+|bc| (~7), safe in f32.
        eA[inst][hh] = (gi < (long)N) ? expf(A) : 0.f;
    }
    __syncthreads();

    if (t < 2){
        float s = 0.f;
        for (int i = 0; i < 128; ++i) s += eA[i][t];
        psum[gb * 2 + t] = s;
    }

    // ---- phase 2: pooling partials sum(e * x) over this block's instances ----
    {
        const int ui = t >> 2, q = t & 3;   // ui: uint channel 0..63, q: quarter
        const int hh = ui >> 5;
        float p0 = 0.f, p1 = 0.f;
        #pragma unroll 4
        for (int i = 0; i < 32; ++i){
            const int inst = q * 32 + i;
            u32 u = *(const u32*)(xbf + ((long)gb * 128 + inst) * 128 + ui * 2);
            float e = eA[inst][hh];
            p0 += e * bf2f(u & 0xffffu);
            p1 += e * bf2f(u >> 16);
        }
        partials[(size_t)gb * 512 + ui * 8 + 0 + q] = p0;
        partials[(size_t)gb * 512 + ui * 8 + 4 + q] = p1;
    }
}

// ---------------------------------------------------------------------------
// K3a: first-stage reduction over the nb dimension. 128 blocks x 256 threads.
// ---------------------------------------------------------------------------
__global__ __launch_bounds__(256)
void reduce1(const float* __restrict__ partials, const float* __restrict__ psum,
             float* __restrict__ red, int nb){
    const int b = blockIdx.x, t = threadIdx.x;
    float a0 = 0.f, a1 = 0.f;
    for (int r = b; r < nb; r += 128){
        a0 += partials[(size_t)r * 512 + t];
        a1 += partials[(size_t)r * 512 + t + 256];
    }
    red[b * 520 + t]       = a0;
    red[b * 520 + t + 256] = a1;
    if (t < 2){
        float s = 0.f;
        for (int r = b; r < nb; r += 128) s += psum[r * 2 + t];
        red[b * 520 + 512 + t] = s;
    }
}

// ---------------------------------------------------------------------------
// K3b: combine 128 reduced rows (f64), M, logits, sigmoid, Y_hat. One block.
// ---------------------------------------------------------------------------
__global__ __launch_bounds__(256)
void finalize2(const float* __restrict__ red, const float* __restrict__ Wcls,
               const float* __restrict__ bcls, float* __restrict__ out){
    __shared__ double colD[512];
    __shared__ double den[2];
    __shared__ float  M_s[128];
    const int t = threadIdx.x;
    double d0 = 0.0, d1 = 0.0;
    for (int r = 0; r < 128; ++r){
        d0 += (double)red[r * 520 + t];
        d1 += (double)red[r * 520 + t + 256];
    }
    colD[t]       = d0;
    colD[t + 256] = d1;
    if (t < 2){
        double s = 0.0;
        for (int r = 0; r < 128; ++r) s += (double)red[r * 520 + 512 + t];
        den[t] = s;
    }
    __syncthreads();
    if (t < 128){
        const double* p = &colD[(t >> 1) * 8 + (t & 1) * 4];
        M_s[t] = (float)((p[0] + p[1] + p[2] + p[3]) / den[t >> 6]);
    }
    __syncthreads();
    if (t == 0){
        double lg = (double)bcls[0];
        for (int c = 0; c < 128; ++c) lg += (double)M_s[c] * (double)Wcls[c];
        float pr = (float)(1.0 / (1.0 + exp(-lg)));
        out[0] = pr;
        out[1] = (lg >= 0.0) ? 1.f : 0.f;
    }
}

// ---------------------------------------------------------------------------
extern "C" void kernel_launch(void* const* d_in, const int* in_sizes, int n_in,
                              void* d_out, int out_size, void* d_ws, size_t ws_size,
                              hipStream_t stream){
    const float* hG   = (const float*)d_in[0];
    const float* W0   = (const float*)d_in[1];
    const float* b0   = (const float*)d_in[2];
    const float* Wa   = (const float*)d_in[3];
    const float* ba   = (const float*)d_in[4];
    const float* Wb   = (const float*)d_in[5];
    const float* bb   = (const float*)d_in[6];
    const float* Wc   = (const float*)d_in[7];
    const float* bc   = (const float*)d_in[8];
    const float* Wcls = (const float*)d_in[9];
    const float* bcls = (const float*)d_in[10];

    const int N    = in_sizes[0] / L_IN;
    const int nb   = (N + 127) / 128;    // 128-row blocks (attn_pool, xbf alloc)
    const int nw   = (N + 15) / 16;      // 16-row wave tiles
    const int nbg  = (nw + 3) / 4;       // 4 waves per block

    char* ws = (char*)d_ws;
    u16* Wt   = (u16*)ws;                                  // 13*8192*2 = 212992 B
    u16* xbf  = (u16*)(ws + 262144);                       // nb*128*128*2 B
    size_t xbytes = (size_t)nb * 128 * 128 * 2;
    size_t poff   = 262144 + ((xbytes + 4095) & ~(size_t)4095);
    float* partials = (float*)(ws + poff);                 // nb*512 f32
    float* psum     = partials + (size_t)nb * 512;         // nb*2 f32
    size_t roff     = poff + (((size_t)nb * 514 * 4 + 4095) & ~(size_t)4095);
    float* red      = (float*)(ws + roff);                 // 128*520 f32 = 266 KB

    prep_w0  <<<(KPAD * 128 + 255) / 256, 256, 0, stream>>>(W0, Wt);
    fc_gemm  <<<nbg, 256, 0, stream>>>(hG, Wt, b0, xbf, N);
    attn_pool<<<nb, 256, 0, stream>>>(xbf, Wa, ba, Wb, bb, Wc, bc, partials, psum, N);
    reduce1  <<<128, 256, 0, stream>>>(partials, psum, red, nb);
    finalize2<<<1, 256, 0, stream>>>(red, Wcls, bcls, (float*)d_out);
}

// Round 6
// 184.641 us; speedup vs baseline: 1.5863x; 1.5863x over previous
//
#include <hip/hip_runtime.h>
#include <stdint.h>

typedef unsigned short u16;
typedef unsigned int   u32;
typedef __bf16 bf16x8 __attribute__((ext_vector_type(8)));
typedef float  f32x4  __attribute__((ext_vector_type(4)));
typedef u32    u32x4  __attribute__((ext_vector_type(4)));

#define L_IN 784
#define KPAD 832
#define KT_N 13

__device__ __forceinline__ u32 f2bf(float f){
    u32 u = __float_as_uint(f);
    return (u + 0x7fffu + ((u >> 16) & 1u)) >> 16;   // RNE truncate to bf16
}
__device__ __forceinline__ float bf2f(u32 s){ return __uint_as_float(s << 16); }

__device__ __forceinline__ void gload16(const void* g, void* l){
    __builtin_amdgcn_global_load_lds(
        (const __attribute__((address_space(1))) unsigned char*)g,
        (__attribute__((address_space(3))) unsigned char*)l, 16, 0, 0);
}

// ---------------------------------------------------------------------------
// K0: W0 [784][128] f32 -> Bimg in MFMA-fragment-broadcast layout:
// Bimg[((kt*2+kk)*8 + nt)*512 + lane*8 + j] = W0[k][col]  (bf16)
//   where lr=lane&15, lk=lane>>4, col = nt*16+lr, k = kt*64+kk*32+lk*8+j.
// A wave's B-fragment load is then ONE contiguous 1KB block (+lane*16):
// 8 fully-used cache lines per instruction, identical for all waves (L1 hit).
// ---------------------------------------------------------------------------
__global__ void prep_w0(const float* __restrict__ W0, u16* __restrict__ Bimg){
    int idx = blockIdx.x * 256 + threadIdx.x;        // 13*8192 = 106496 total
    if (idx >= KPAD * 128) return;
    int j  = idx & 7;
    int l  = (idx >> 3) & 63;
    int nt = (idx >> 9) & 7;
    int kk = (idx >> 12) & 1;
    int kt = idx >> 13;
    int col = nt * 16 + (l & 15);
    int k   = kt * 64 + kk * 32 + (l >> 4) * 8 + j;
    float v = (k < L_IN) ? W0[k * 128 + col] : 0.f;
    Bimg[idx] = (u16)f2bf(v);
}

// ---------------------------------------------------------------------------
// K1: x = relu(h @ W0 + b0). Transaction-minimal MFMA GEMM, tile 64x128:
//  - A: global_load_lds f32 staging, LINEAR LDS dest (rule 21), fully
//    coalesced source (4 rows x 16 granules = 8 full 128B lines per
//    wave-instr); chunk32 XOR q^(row&3) pre-applied on the SOURCE address,
//    undone on the ds_read side -> <=4-way bank aliasing.
//  - B: 1KB contiguous fragment-broadcast loads from Bimg (L1-resident).
//  - One barrier per K-tile; B loads issued before the next-tile stage so
//    the pre-MFMA vmcnt waits (12 / 4) keep the stage DMA in flight.
// ---------------------------------------------------------------------------
__global__ __launch_bounds__(256, 4)
void fc_gemm(const float* __restrict__ hG, const u16* __restrict__ Bimg,
             const float* __restrict__ b0, u16* __restrict__ xbf, int N){
    __shared__ __align__(16) float As[2][64 * 64];   // 2 x 16 KB, linear

    const int t    = threadIdx.x;
    const int lane = t & 63;
    const int w    = t >> 6;
    const int lr   = lane & 15;          // A-row / B-col within 16
    const int lk   = lane >> 4;          // k-slot 0..3
    const long rowBase = (long)blockIdx.x * 64;

    // ---- staging geometry: thread t owns granules g = j*256+t (16B each).
    // dest = linear g*16. row = g>>4 = j*16+(t>>4); granule-in-row c = t&15.
    // chunk32 swizzle on SOURCE: c' = c ^ ((row&3)<<1) (stays in the same
    // 256B row segment -> still 8 fully-used lines per wave-instr).
    const int rloc = t >> 4;                  // row base within j-group
    const int csw  = (t & 15) ^ ((rloc & 3) << 1);
    const float* srcp[4];
    #pragma unroll
    for (int j = 0; j < 4; ++j){
        long grow = rowBase + j * 16 + rloc;
        if (grow >= N) grow = N - 1;          // clamp; stores are guarded
        srcp[j] = hG + grow * L_IN + csw * 4;
    }

    f32x4 acc[8];
    #pragma unroll
    for (int nt = 0; nt < 8; ++nt) acc[nt] = (f32x4)0.f;

    auto stage = [&](int kt, int buf){
        #pragma unroll
        for (int j = 0; j < 4; ++j){
            // k of this granule = kt*64 + csw*4; pad region only at kt==12,
            // csw>=4 -> clamp to k=0 of same row (B is zero there).
            const float* src = (kt == KT_N - 1 && csw >= 4)
                             ? (srcp[j] - csw * 4)
                             : (srcp[j] + kt * 64);
            gload16(src, (char*)&As[buf][0] + (j * 256 + t) * 16);
        }
    };

    // prologue: stage tile 0 into buffer 0
    stage(0, 0);

    int cur = 0;
    const int rA = w * 16 + lr;              // this lane's A row in the tile

    #pragma unroll 1
    for (int kt = 0; kt < KT_N; ++kt){
        __syncthreads();    // drains vmcnt(0): stage(kt) visible in LDS

        // ---- B fragments kk=0 (oldest in FIFO) ----
        const u16* bp = Bimg + (size_t)(kt * 2) * 4096 + lane * 8;
        bf16x8 b0f[8];
        #pragma unroll
        for (int nt = 0; nt < 8; ++nt)
            b0f[nt] = *(const bf16x8*)(bp + nt * 512);

        // ---- stage next tile (younger: survives the bfr vmcnt waits) ----
        if (kt + 1 < KT_N) stage(kt + 1, cur ^ 1);

        // ---- B fragments kk=1 (youngest) ----
        bf16x8 b1f[8];
        #pragma unroll
        for (int nt = 0; nt < 8; ++nt)
            b1f[nt] = *(const bf16x8*)(bp + 4096 + nt * 512);

        // ---- A from LDS + MFMA, kk = 0 then 1 ----
        #pragma unroll
        for (int kk = 0; kk < 2; ++kk){
            const int q = kk * 4 + (lk ^ (rA & 3));   // swizzled chunk32
            f32x4 lo = *(const f32x4*)&As[cur][rA * 64 + q * 8];
            f32x4 hi = *(const f32x4*)&As[cur][rA * 64 + q * 8 + 4];
            bf16x8 af;
            #pragma unroll
            for (int j = 0; j < 4; ++j){
                af[j]     = (__bf16)lo[j];
                af[4 + j] = (__bf16)hi[j];
            }
            #pragma unroll
            for (int nt = 0; nt < 8; ++nt)
                acc[nt] = __builtin_amdgcn_mfma_f32_16x16x32_bf16(
                              af, kk ? b1f[nt] : b0f[nt], acc[nt], 0, 0, 0);
        }
        cur ^= 1;
    }

    // ---- epilogue: + bias, relu, store bf16 ----
    #pragma unroll
    for (int nt = 0; nt < 8; ++nt){
        int col = nt * 16 + lr;
        float bias = b0[col];
        long row0 = rowBase + w * 16 + lk * 4;
        #pragma unroll
        for (int r = 0; r < 4; ++r){
            long row = row0 + r;
            if (row < (long)N){
                float v = acc[nt][r] + bias;
                v = v > 0.f ? v : 0.f;
                xbf[(size_t)row * 128 + col] = (u16)f2bf(v);
            }
        }
    }
}

// ---------------------------------------------------------------------------
// K2: gated attention logits + exp + block pooling partials.
// ---------------------------------------------------------------------------
__global__ __launch_bounds__(256, 2)
void attn_pool(const u16* __restrict__ xbf,
               const float* __restrict__ Wa, const float* __restrict__ ba,
               const float* __restrict__ Wb, const float* __restrict__ bb,
               const float* __restrict__ Wc, const float* __restrict__ bc,
               float* __restrict__ partials, float* __restrict__ psum, int N){
    __shared__ __align__(16) float Wa_s[4096], Wb_s[4096];
    __shared__ float ba_s[64], bb_s[64], Wc_s[64], bc_s[2];
    __shared__ float eA[128][2];

    const int t  = threadIdx.x;
    const int gb = blockIdx.x;

    for (int i = t; i < 4096; i += 256){ Wa_s[i] = Wa[i]; Wb_s[i] = Wb[i]; }
    if (t < 64){ ba_s[t] = ba[t]; bb_s[t] = bb[t]; Wc_s[t] = Wc[t]; }
    if (t < 2)  bc_s[t] = bc[t];
    __syncthreads();

    // ---- phase 1: attention logit per (instance, head) ----
    {
        const int inst = t & 127, hh = t >> 7;
        const long gi = (long)gb * 128 + inst;
        float aa[32], ag[32];
        #pragma unroll
        for (int d = 0; d < 32; ++d){ aa[d] = ba_s[hh*32+d]; ag[d] = bb_s[hh*32+d]; }
        const float* wa = &Wa_s[hh * 2048];
        const float* wb = &Wb_s[hh * 2048];
        const u16*   xp = xbf + gi * 128 + hh * 64;
        for (int c = 0; c < 8; ++c){
            u32x4 xc = *(const u32x4*)(xp + c * 8);
            #pragma unroll
            for (int s8 = 0; s8 < 8; ++s8){
                u32 uw = xc[s8 >> 1];
                float xv = bf2f((s8 & 1) ? (uw >> 16) : (uw & 0xffffu));
                const int s = c * 8 + s8;
                #pragma unroll
                for (int q = 0; q < 8; ++q){
                    f32x4 w4 = *(const f32x4*)(wa + s * 32 + q * 4);
                    f32x4 v4 = *(const f32x4*)(wb + s * 32 + q * 4);
                    aa[q*4+0] += xv * w4[0]; aa[q*4+1] += xv * w4[1];
                    aa[q*4+2] += xv * w4[2]; aa[q*4+3] += xv * w4[3];
                    ag[q*4+0] += xv * v4[0]; ag[q*4+1] += xv * v4[1];
                    ag[q*4+2] += xv * v4[2]; ag[q*4+3] += xv * v4[3];
                }
            }
        }
        float A = bc_s[hh];
        #pragma unroll
        for (int d = 0; d < 32; ++d){
            float av = tanhf(aa[d]);
            float gv = 1.f / (1.f + expf(-ag[d]));
            A += av * gv * Wc_s[hh*32+d];
        }
        // exp without max-subtraction: |A| <= sum|Wc|+|bc| (~7), safe in f32.
        eA[inst][hh] = (gi < (long)N) ? expf(A) : 0.f;
    }
    __syncthreads();

    if (t < 2){
        float s = 0.f;
        for (int i = 0; i < 128; ++i) s += eA[i][t];
        psum[gb * 2 + t] = s;
    }

    // ---- phase 2: pooling partials sum(e * x) over this block's instances ----
    {
        const int ui = t >> 2, q = t & 3;   // ui: uint channel 0..63, q: quarter
        const int hh = ui >> 5;
        float p0 = 0.f, p1 = 0.f;
        #pragma unroll 4
        for (int i = 0; i < 32; ++i){
            const int inst = q * 32 + i;
            u32 u = *(const u32*)(xbf + ((long)gb * 128 + inst) * 128 + ui * 2);
            float e = eA[inst][hh];
            p0 += e * bf2f(u & 0xffffu);
            p1 += e * bf2f(u >> 16);
        }
        partials[(size_t)gb * 512 + ui * 8 + 0 + q] = p0;
        partials[(size_t)gb * 512 + ui * 8 + 4 + q] = p1;
    }
}

// ---------------------------------------------------------------------------
// K3a: first-stage reduction over the nb dimension. 128 blocks x 256 threads.
// ---------------------------------------------------------------------------
__global__ __launch_bounds__(256)
void reduce1(const float* __restrict__ partials, const float* __restrict__ psum,
             float* __restrict__ red, int nb){
    const int b = blockIdx.x, t = threadIdx.x;
    float a0 = 0.f, a1 = 0.f;
    for (int r = b; r < nb; r += 128){
        a0 += partials[(size_t)r * 512 + t];
        a1 += partials[(size_t)r * 512 + t + 256];
    }
    red[b * 520 + t]       = a0;
    red[b * 520 + t + 256] = a1;
    if (t < 2){
        float s = 0.f;
        for (int r = b; r < nb; r += 128) s += psum[r * 2 + t];
        red[b * 520 + 512 + t] = s;
    }
}

// ---------------------------------------------------------------------------
// K3b: combine 128 reduced rows (f64), M, logits, sigmoid, Y_hat. One block.
// ---------------------------------------------------------------------------
__global__ __launch_bounds__(256)
void finalize2(const float* __restrict__ red, const float* __restrict__ Wcls,
               const float* __restrict__ bcls, float* __restrict__ out){
    __shared__ double colD[512];
    __shared__ double den[2];
    __shared__ float  M_s[128];
    const int t = threadIdx.x;
    double d0 = 0.0, d1 = 0.0;
    for (int r = 0; r < 128; ++r){
        d0 += (double)red[r * 520 + t];
        d1 += (double)red[r * 520 + t + 256];
    }
    colD[t]       = d0;
    colD[t + 256] = d1;
    if (t < 2){
        double s = 0.0;
        for (int r = 0; r < 128; ++r) s += (double)red[r * 520 + 512 + t];
        den[t] = s;
    }
    __syncthreads();
    if (t < 128){
        const double* p = &colD[(t >> 1) * 8 + (t & 1) * 4];
        M_s[t] = (float)((p[0] + p[1] + p[2] + p[3]) / den[t >> 6]);
    }
    __syncthreads();
    if (t == 0){
        double lg = (double)bcls[0];
        for (int c = 0; c < 128; ++c) lg += (double)M_s[c] * (double)Wcls[c];
        float pr = (float)(1.0 / (1.0 + exp(-lg)));
        out[0] = pr;
        out[1] = (lg >= 0.0) ? 1.f : 0.f;
    }
}

// ---------------------------------------------------------------------------
extern "C" void kernel_launch(void* const* d_in, const int* in_sizes, int n_in,
                              void* d_out, int out_size, void* d_ws, size_t ws_size,
                              hipStream_t stream){
    const float* hG   = (const float*)d_in[0];
    const float* W0   = (const float*)d_in[1];
    const float* b0   = (const float*)d_in[2];
    const float* Wa   = (const float*)d_in[3];
    const float* ba   = (const float*)d_in[4];
    const float* Wb   = (const float*)d_in[5];
    const float* bb   = (const float*)d_in[6];
    const float* Wc   = (const float*)d_in[7];
    const float* bc   = (const float*)d_in[8];
    const float* Wcls = (const float*)d_in[9];
    const float* bcls = (const float*)d_in[10];

    const int N    = in_sizes[0] / L_IN;
    const int nb   = (N + 127) / 128;    // 128-row blocks (attn_pool, xbf alloc)
    const int nb64 = (N + 63) / 64;      // 64-row GEMM tiles

    char* ws = (char*)d_ws;
    u16* Bimg = (u16*)ws;                                  // 13*8192*2 = 212992 B
    u16* xbf  = (u16*)(ws + 262144);                       // nb*128*128*2 B
    size_t xbytes = (size_t)nb * 128 * 128 * 2;
    size_t poff   = 262144 + ((xbytes + 4095) & ~(size_t)4095);
    float* partials = (float*)(ws + poff);                 // nb*512 f32
    float* psum     = partials + (size_t)nb * 512;         // nb*2 f32
    size_t roff     = poff + (((size_t)nb * 514 * 4 + 4095) & ~(size_t)4095);
    float* red      = (float*)(ws + roff);                 // 128*520 f32 = 266 KB

    prep_w0  <<<(KPAD * 128 + 255) / 256, 256, 0, stream>>>(W0, Bimg);
    fc_gemm  <<<nb64, 256, 0, stream>>>(hG, Bimg, b0, xbf, N);
    attn_pool<<<nb, 256, 0, stream>>>(xbf, Wa, ba, Wb, bb, Wc, bc, partials, psum, N);
    reduce1  <<<128, 256, 0, stream>>>(partials, psum, red, nb);
    finalize2<<<1, 256, 0, stream>>>(red, Wcls, bcls, (float*)d_out);
}

// Round 7
// 125.258 us; speedup vs baseline: 2.3384x; 1.4741x over previous
//
#include <hip/hip_runtime.h>
#include <stdint.h>
#include <math.h>

typedef unsigned short u16;
typedef unsigned int   u32;
typedef __bf16 bf16x8 __attribute__((ext_vector_type(8)));
typedef float  f32x4  __attribute__((ext_vector_type(4)));

#define L_IN 784
#define KPAD 832
#define KT_N 13

__device__ __forceinline__ u32 f2bf(float f){
    u32 u = __float_as_uint(f);
    return (u + 0x7fffu + ((u >> 16) & 1u)) >> 16;   // RNE truncate to bf16
}

__device__ __forceinline__ void gload16(const void* g, void* l){
    __builtin_amdgcn_global_load_lds(
        (const __attribute__((address_space(1))) unsigned char*)g,
        (__attribute__((address_space(3))) unsigned char*)l, 16, 0, 0);
}

// ---------------------------------------------------------------------------
// K0a: W0 [784][128] f32 -> Bimg in MFMA-fragment-broadcast layout (validated
// round 6): Bimg[((kt*2+kk)*8+nt)*512 + lane*8 + j] = W0[k][col] bf16, where
// col = nt*16+(l&15), k = kt*64+kk*32+(l>>4)*8+j. Wave B-load = 1KB contig.
// ---------------------------------------------------------------------------
__global__ void prep_w0(const float* __restrict__ W0, u16* __restrict__ Bimg){
    int idx = blockIdx.x * 256 + threadIdx.x;        // 13*8192 = 106496 total
    if (idx >= KPAD * 128) return;
    int j  = idx & 7;
    int l  = (idx >> 3) & 63;
    int nt = (idx >> 9) & 7;
    int kk = (idx >> 12) & 1;
    int kt = idx >> 13;
    int col = nt * 16 + (l & 15);
    int k   = kt * 64 + kk * 32 + (l >> 4) * 8 + j;
    float v = (k < L_IN) ? W0[k * 128 + col] : 0.f;
    Bimg[idx] = (u16)f2bf(v);
}

// ---------------------------------------------------------------------------
// K0b: Wa/Wb [2][64][32] f32 -> Wab fragment-broadcast bf16 image for the
// attention projection MFMAs. Block b = mat*8 + h*4 + nt*2 + ks (16 blocks of
// 512 elems = 16KB): Wab[(b<<9) + l*8 + jj] = W[h][s][d],
//   s = ks*32 + (l>>4)*8 + jj,  d = nt*16 + (l&15).
// ---------------------------------------------------------------------------
__global__ void prep_wab(const float* __restrict__ Wa, const float* __restrict__ Wb,
                         u16* __restrict__ Wab){
    int idx = blockIdx.x * 256 + threadIdx.x;        // 16384 total
    if (idx >= 16384) return;
    int jj  = idx & 7;
    int l   = (idx >> 3) & 63;
    int ks  = (idx >> 9) & 1;
    int nt  = (idx >> 10) & 1;
    int h   = (idx >> 11) & 1;
    int mat = (idx >> 12) & 1;
    int s = ks * 32 + (l >> 4) * 8 + jj;
    int d = nt * 16 + (l & 15);
    const float* W = mat ? Wb : Wa;
    Wab[idx] = (u16)f2bf(W[h * 2048 + s * 32 + d]);
}

// ---------------------------------------------------------------------------
// K1: FUSED x = relu(h@W0+b0)  ->  gated-attention logits -> exp -> pooling
// partials. GEMM loop identical to round 6 (transaction-minimal, validated).
// Epilogue: x-tile -> LDS bf16 (swizzled), per-head MFMA projections
// (x[16x64] @ Wa/Wb[64x32]), tanh*sigmoid*Wc dot via shfl_xor butterfly,
// e = exp(A), pooling sum(e*x) from f32 acc regs. x NEVER goes to global.
// Per block output: 130 floats (128 col-partials + 2 e-sums).
// ---------------------------------------------------------------------------
__global__ __launch_bounds__(256, 4)
void fc_fused(const float* __restrict__ hG, const u16* __restrict__ Bimg,
              const u16* __restrict__ Wab, const float* __restrict__ b0,
              const float* __restrict__ ba, const float* __restrict__ bb,
              const float* __restrict__ Wc, const float* __restrict__ bc,
              float* __restrict__ partials, int N){
    __shared__ __align__(16) float As[2][64 * 64];   // 2 x 16 KB, linear

    const int t    = threadIdx.x;
    const int lane = t & 63;
    const int w    = t >> 6;
    const int lr   = lane & 15;          // A-row / B-col within 16
    const int lk   = lane >> 4;          // k-slot 0..3
    const int gb   = blockIdx.x;
    const long rowBase = (long)gb * 64;

    // ---- staging geometry (round 6, validated) ----
    const int rloc = t >> 4;
    const int csw  = (t & 15) ^ ((rloc & 3) << 1);
    const float* srcp[4];
    #pragma unroll
    for (int j = 0; j < 4; ++j){
        long grow = rowBase + j * 16 + rloc;
        if (grow >= N) grow = N - 1;
        srcp[j] = hG + grow * L_IN + csw * 4;
    }

    f32x4 acc[8];
    #pragma unroll
    for (int nt = 0; nt < 8; ++nt) acc[nt] = (f32x4)0.f;

    auto stage = [&](int kt, int buf){
        #pragma unroll
        for (int j = 0; j < 4; ++j){
            const float* src = (kt == KT_N - 1 && csw >= 4)
                             ? (srcp[j] - csw * 4)
                             : (srcp[j] + kt * 64);
            gload16(src, (char*)&As[buf][0] + (j * 256 + t) * 16);
        }
    };

    stage(0, 0);
    int cur = 0;
    const int rA = w * 16 + lr;

    #pragma unroll 1
    for (int kt = 0; kt < KT_N; ++kt){
        __syncthreads();

        const u16* bp = Bimg + (size_t)(kt * 2) * 4096 + lane * 8;
        bf16x8 b0f[8];
        #pragma unroll
        for (int nt = 0; nt < 8; ++nt)
            b0f[nt] = *(const bf16x8*)(bp + nt * 512);

        if (kt + 1 < KT_N) stage(kt + 1, cur ^ 1);

        bf16x8 b1f[8];
        #pragma unroll
        for (int nt = 0; nt < 8; ++nt)
            b1f[nt] = *(const bf16x8*)(bp + 4096 + nt * 512);

        #pragma unroll
        for (int kk = 0; kk < 2; ++kk){
            const int q = kk * 4 + (lk ^ (rA & 3));
            f32x4 lo = *(const f32x4*)&As[cur][rA * 64 + q * 8];
            f32x4 hi = *(const f32x4*)&As[cur][rA * 64 + q * 8 + 4];
            bf16x8 af;
            #pragma unroll
            for (int j = 0; j < 4; ++j){
                af[j]     = (__bf16)lo[j];
                af[4 + j] = (__bf16)hi[j];
            }
            #pragma unroll
            for (int nt = 0; nt < 8; ++nt)
                acc[nt] = __builtin_amdgcn_mfma_f32_16x16x32_bf16(
                              af, kk ? b1f[nt] : b0f[nt], acc[nt], 0, 0, 0);
        }
        cur ^= 1;
    }

    __syncthreads();   // all waves done reading As -> safe to repurpose LDS

    // ---- bias + relu in place; write x-tile bf16 to LDS (swizzled) ----
    // acc[nt][j]: row_local = w*16 + lk*4 + j, col = nt*16 + lr.
    // xs[row*128 + (((col>>3)^(row&15))<<3) + (col&7)]
    u16*   xs   = (u16*)&As[0][0];        // 64 x 128 bf16 = 16 KB
    float* pbuf = &As[1][0];              // 4 x 132 f32 cross-wave buffer
    #pragma unroll
    for (int nt = 0; nt < 8; ++nt){
        float bias = b0[nt * 16 + lr];
        #pragma unroll
        for (int j = 0; j < 4; ++j){
            float v = acc[nt][j] + bias;
            v = v > 0.f ? v : 0.f;
            acc[nt][j] = v;
            int row = w * 16 + lk * 4 + j;
            int col = nt * 16 + lr;
            xs[row * 128 + ((((col >> 3) ^ (row & 15))) << 3) + (col & 7)] = (u16)f2bf(v);
        }
    }
    __syncthreads();

    // ---- per-head projections via MFMA + logits + exp ----
    float eh[2][4];
    #pragma unroll
    for (int h = 0; h < 2; ++h){
        // A-fragments: row = w*16 + lr, k = h*64 + ks*32 + lk*8 (+0..7)
        bf16x8 xa[2];
        #pragma unroll
        for (int ks = 0; ks < 2; ++ks){
            int row = w * 16 + lr;
            int ch  = (h * 8 + ks * 4 + lk) ^ (row & 15);
            xa[ks] = *(const bf16x8*)&xs[row * 128 + ch * 8];
        }
        f32x4 Ca[2], Cg[2];
        #pragma unroll
        for (int nt = 0; nt < 2; ++nt){ Ca[nt] = (f32x4)0.f; Cg[nt] = (f32x4)0.f; }
        #pragma unroll
        for (int nt = 0; nt < 2; ++nt)
            #pragma unroll
            for (int ks = 0; ks < 2; ++ks){
                bf16x8 wfa = *(const bf16x8*)(Wab + ((size_t)((0*8) + h*4 + nt*2 + ks) << 9) + lane * 8);
                bf16x8 wfb = *(const bf16x8*)(Wab + ((size_t)((1*8) + h*4 + nt*2 + ks) << 9) + lane * 8);
                Ca[nt] = __builtin_amdgcn_mfma_f32_16x16x32_bf16(xa[ks], wfa, Ca[nt], 0, 0, 0);
                Cg[nt] = __builtin_amdgcn_mfma_f32_16x16x32_bf16(xa[ks], wfb, Cg[nt], 0, 0, 0);
            }
        // C-layout: col(d within 16) = lr, row(instance within 16) = lk*4+j
        float pj[4];
        #pragma unroll
        for (int j = 0; j < 4; ++j){
            float s = 0.f;
            #pragma unroll
            for (int nt = 0; nt < 2; ++nt){
                int d = h * 32 + nt * 16 + lr;
                float av = tanhf(Ca[nt][j] + ba[d]);
                float gv = 1.f / (1.f + expf(-(Cg[nt][j] + bb[d])));
                s += av * gv * Wc[d];
            }
            pj[j] = s;
        }
        #pragma unroll
        for (int m = 1; m <= 8; m <<= 1)
            #pragma unroll
            for (int j = 0; j < 4; ++j)
                pj[j] += __shfl_xor(pj[j], m, 64);
        #pragma unroll
        for (int j = 0; j < 4; ++j){
            long row = rowBase + w * 16 + lk * 4 + j;
            // |A| <= sum|Wc|+|bc| (~7): exp safe in f32 without max-subtract
            eh[h][j] = (row < (long)N) ? expf(pj[j] + bc[h]) : 0.f;
        }
    }

    // ---- pooling: p[col] = sum over wave's 16 rows of e*x (from f32 acc) ----
    float p[8];
    #pragma unroll
    for (int nt = 0; nt < 8; ++nt){
        const int h = nt >> 2;
        float s = 0.f;
        #pragma unroll
        for (int j = 0; j < 4; ++j) s += eh[h][j] * acc[nt][j];
        p[nt] = s;
    }
    #pragma unroll
    for (int m = 16; m <= 32; m <<= 1)
        #pragma unroll
        for (int nt = 0; nt < 8; ++nt)
            p[nt] += __shfl_xor(p[nt], m, 64);
    float es0 = eh[0][0] + eh[0][1] + eh[0][2] + eh[0][3];
    float es1 = eh[1][0] + eh[1][1] + eh[1][2] + eh[1][3];
    es0 += __shfl_xor(es0, 16, 64); es0 += __shfl_xor(es0, 32, 64);
    es1 += __shfl_xor(es1, 16, 64); es1 += __shfl_xor(es1, 32, 64);

    if (lk == 0){
        #pragma unroll
        for (int nt = 0; nt < 8; ++nt)
            pbuf[w * 132 + nt * 16 + lr] = p[nt];
    }
    if (lane == 0){
        pbuf[w * 132 + 128] = es0;
        pbuf[w * 132 + 129] = es1;
    }
    __syncthreads();
    if (t < 130){
        float s = pbuf[t] + pbuf[132 + t] + pbuf[264 + t] + pbuf[396 + t];
        partials[(size_t)gb * 132 + t] = s;
    }
}

// ---------------------------------------------------------------------------
// K2: first-stage reduction over blocks. 128 blocks x 256 threads; block b
// sums partial rows b, b+128, ... -> red[b][132] (cols 0-127 pool, 128-129 e).
// ---------------------------------------------------------------------------
__global__ __launch_bounds__(256)
void reduce1(const float* __restrict__ partials, float* __restrict__ red, int nb){
    const int b = blockIdx.x, t = threadIdx.x;
    if (t >= 130) return;
    float a = 0.f;
    for (int r = b; r < nb; r += 128)
        a += partials[(size_t)r * 132 + t];
    red[b * 132 + t] = a;
}

// ---------------------------------------------------------------------------
// K3: combine 128 reduced rows (f64), M, logits, sigmoid, Y_hat. One block.
// ---------------------------------------------------------------------------
__global__ __launch_bounds__(256)
void finalize2(const float* __restrict__ red, const float* __restrict__ Wcls,
               const float* __restrict__ bcls, float* __restrict__ out){
    __shared__ double colD[130];
    __shared__ float  M_s[128];
    const int t = threadIdx.x;
    if (t < 130){
        double s = 0.0;
        for (int r = 0; r < 128; ++r) s += (double)red[r * 132 + t];
        colD[t] = s;
    }
    __syncthreads();
    if (t < 128)
        M_s[t] = (float)(colD[t] / colD[128 + (t >> 6)]);
    __syncthreads();
    if (t == 0){
        double lg = (double)bcls[0];
        for (int c = 0; c < 128; ++c) lg += (double)M_s[c] * (double)Wcls[c];
        float pr = (float)(1.0 / (1.0 + exp(-lg)));
        out[0] = pr;
        out[1] = (lg >= 0.0) ? 1.f : 0.f;
    }
}

// ---------------------------------------------------------------------------
extern "C" void kernel_launch(void* const* d_in, const int* in_sizes, int n_in,
                              void* d_out, int out_size, void* d_ws, size_t ws_size,
                              hipStream_t stream){
    const float* hG   = (const float*)d_in[0];
    const float* W0   = (const float*)d_in[1];
    const float* b0   = (const float*)d_in[2];
    const float* Wa   = (const float*)d_in[3];
    const float* ba   = (const float*)d_in[4];
    const float* Wb   = (const float*)d_in[5];
    const float* bb   = (const float*)d_in[6];
    const float* Wc   = (const float*)d_in[7];
    const float* bc   = (const float*)d_in[8];
    const float* Wcls = (const float*)d_in[9];
    const float* bcls = (const float*)d_in[10];

    const int N    = in_sizes[0] / L_IN;
    const int nb64 = (N + 63) / 64;      // 64-row fused tiles

    char* ws = (char*)d_ws;
    u16* Bimg = (u16*)ws;                                  // 212992 B
    u16* Wab  = (u16*)(ws + 262144);                       // 16384 B
    size_t poff = 262144 + 16384;                          // 278528 (4K-aligned)
    float* partials = (float*)(ws + poff);                 // nb64*132 f32
    size_t roff = poff + (((size_t)nb64 * 132 * 4 + 4095) & ~(size_t)4095);
    float* red  = (float*)(ws + roff);                     // 128*132 f32

    prep_w0  <<<(KPAD * 128 + 255) / 256, 256, 0, stream>>>(W0, Bimg);
    prep_wab <<<64, 256, 0, stream>>>(Wa, Wb, Wab);
    fc_fused <<<nb64, 256, 0, stream>>>(hG, Bimg, Wab, b0, ba, bb, Wc, bc,
                                        partials, N);
    reduce1  <<<128, 256, 0, stream>>>(partials, red, nb64);
    finalize2<<<1, 256, 0, stream>>>(red, Wcls, bcls, (float*)d_out);
}